// Round 5
// baseline (333.071 us; speedup 1.0000x reference)
//
#include <hip/hip_runtime.h>
#include <math.h>
#include <stdint.h>

// Problem: ProcessFeatures_83296595738632
// corr[bs,bg,i] = sum_{h,j,k} sat[bs,h,(i+j)%64,k] * grd[bg,h,j,15-k]
// orien = argmax_i corr (first-max); dot with cyclic shift orien, /||sat||
// distance[bg,bs] = 2-2*dot; out: sat | grd | distance | orien(float)
//
// R5: sat rows in VGPRs (lane r = row r of h=wv). grd rows via VMEM
// (base laundered through asm -> compiler cannot scalarize; vmcnt pipeline).
// Rotation of partials via ds_bpermute (the ONLY lgkm op in the hot loop ->
// precise in-order waits). Per (b,j): 16 FMA + 1 bpermute.

#define BS   96
#define H    4
#define W    64
#define C    16
#define BG   96
#define NB   8
#define NTH  256
#define HWC  (H*W*C)

#define SAT_ELEMS (BS*H*W*C)          // 393216
#define OUT_DIST  (2*SAT_ELEMS)       // 786432
#define OUT_ORIEN (OUT_DIST + BS*BG)  // 795648

// satL (dot phase only): chunk c4 of row hw at slot (c4 + (hw>>1)) & 3
__device__ __forceinline__ int satIdx(int hw, int c4) {
    return hw * 16 + 4 * ((c4 + (hw >> 1)) & 3);
}

__device__ __forceinline__ float rot_add(int baddr, float p) {
    return __int_as_float(__builtin_amdgcn_ds_bpermute(baddr, __float_as_int(p)));
}

// sum_k sat[k] * g[15-k], reversed-c pairing; a0..a3 = g[0..3],[4..7],[8..11],[12..15]
__device__ __forceinline__ float dot_rev(const float4 s0, const float4 s1,
                                         const float4 s2, const float4 s3,
                                         const float4 a0, const float4 a1,
                                         const float4 a2, const float4 a3) {
    float p0 = fmaf(s0.x, a3.w, fmaf(s0.y, a3.z, fmaf(s0.z, a3.y, s0.w * a3.x)));
    float p1 = fmaf(s1.x, a2.w, fmaf(s1.y, a2.z, fmaf(s1.z, a2.y, s1.w * a2.x)));
    float p2 = fmaf(s2.x, a1.w, fmaf(s2.y, a1.z, fmaf(s2.z, a1.y, s2.w * a1.x)));
    float p3 = fmaf(s3.x, a0.w, fmaf(s3.y, a0.z, fmaf(s3.z, a0.y, s3.w * a0.x)));
    return (p0 + p1) + (p2 + p3);
}

__global__ __launch_bounds__(NTH)
void pf_fused_kernel(const float* __restrict__ sat,
                     const float* __restrict__ grd,
                     float* __restrict__ out)
{
    __shared__ float satL[H * W * C];     // 16 KB (dot phase)
    __shared__ float partL[NB * 4 * W];   // 8 KB
    __shared__ float sumL[4];
    __shared__ float dotP[NB * 4];
    __shared__ int   orienL[NB];

    const int bs   = blockIdx.y;
    const int bg0  = blockIdx.x * NB;
    const int tid  = threadIdx.x;
    const int wv   = tid >> 6;
    const int lane = tid & 63;

    // ---- sat rows -> registers (coalesced 64B/lane) ----
    const float4* sp = (const float4*)(sat + (((size_t)bs * H + wv) * W + lane) * C);
    const float4 s0 = sp[0], s1 = sp[1], s2 = sp[2], s3 = sp[3];

    // ---- stage satL for the dot phase ----
    {
        const int hw = wv * W + lane;
        *(float4*)&satL[satIdx(hw, 0)] = s0;
        *(float4*)&satL[satIdx(hw, 1)] = s1;
        *(float4*)&satL[satIdx(hw, 2)] = s2;
        *(float4*)&satL[satIdx(hw, 3)] = s3;
    }

    // ---- per-h squared sum (norm) ----
    {
        float a = fmaf(s0.x, s0.x, fmaf(s0.y, s0.y, fmaf(s0.z, s0.z, s0.w * s0.w)));
        float b = fmaf(s1.x, s1.x, fmaf(s1.y, s1.y, fmaf(s1.z, s1.z, s1.w * s1.w)));
        float c = fmaf(s2.x, s2.x, fmaf(s2.y, s2.y, fmaf(s2.z, s2.z, s2.w * s2.w)));
        float d = fmaf(s3.x, s3.x, fmaf(s3.y, s3.y, fmaf(s3.z, s3.z, s3.w * s3.w)));
        float s = (a + b) + (c + d);
        #pragma unroll
        for (int off = 32; off; off >>= 1) s += __shfl_xor(s, off);
        if (lane == 0) sumL[wv] = s;
    }

    // ---- corr: grd via VMEM (laundered base -> no scalarization), bpermute rotate ----
    uint64_t gaddr = (uint64_t)(grd + (size_t)(bg0 * H + wv) * W * C);
    asm volatile("" : "+v"(gaddr));          // opaque VGPR base: forces global_load path
    const float4* gp[NB];
    #pragma unroll
    for (int b = 0; b < NB; ++b)
        gp[b] = (const float4*)(gaddr + (uint64_t)b * (HWC * 4));

    float acc[NB];
    #pragma unroll
    for (int b = 0; b < NB; ++b) acc[b] = 0.f;

    int baddr = lane << 2;                   // bpermute byte addr of lane (lane+j)&63
    #pragma unroll 2
    for (int j = 0; j < W; ++j) {
        #pragma unroll
        for (int b = 0; b < NB; ++b) {
            const float4* g4 = gp[b] + j * 4;   // j*64B fits the 13-bit imm offset
            float4 a0 = g4[0], a1 = g4[1], a2 = g4[2], a3 = g4[3];
            float p = dot_rev(s0, s1, s2, s3, a0, a1, a2, a3);
            acc[b] += rot_add(baddr, p);
        }
        baddr = (baddr + 4) & 255;
    }

    #pragma unroll
    for (int b = 0; b < NB; ++b) partL[(b * 4 + wv) * W + lane] = acc[b];
    __syncthreads();

    // ---- argmax per bg (first-max tie-break) ----
    for (int b = wv; b < NB; b += 4) {
        float v = (partL[(b*4+0)*W + lane] + partL[(b*4+1)*W + lane])
                + (partL[(b*4+2)*W + lane] + partL[(b*4+3)*W + lane]);
        int idx = lane;
        #pragma unroll
        for (int off = 32; off; off >>= 1) {
            float ov = __shfl_xor(v, off);
            int   oi = __shfl_xor(idx, off);
            if (ov > v || (ov == v && oi < idx)) { v = ov; idx = oi; }
        }
        if (lane == 0) {
            orienL[b] = idx;
            out[OUT_ORIEN + bs * BG + (bg0 + b)] = (float)idx;
        }
    }
    __syncthreads();

    const float nrm = sqrtf(sumL[0] + sumL[1] + sumL[2] + sumL[3] + 1e-8f);

    // ---- dot phase: wave = h, lane = j ----
    {
        float dp[NB];
        #pragma unroll
        for (int b = 0; b < NB; ++b) {
            const int row = (lane + orienL[b]) & 63;
            const float* gRow = grd + (((size_t)(bg0 + b) * H + wv) * W + lane) * C;
            float s = 0.f;
            #pragma unroll
            for (int c4 = 0; c4 < 4; ++c4) {
                float4 sv = *(const float4*)&satL[satIdx(wv * W + row, c4)];
                float4 gv = *(const float4*)(gRow + 4 * c4);
                s = fmaf(sv.x, gv.x, fmaf(sv.y, gv.y, fmaf(sv.z, gv.z, fmaf(sv.w, gv.w, s))));
            }
            dp[b] = s;
        }
        #pragma unroll
        for (int b = 0; b < NB; ++b) {
            float s = dp[b];
            #pragma unroll
            for (int off = 32; off; off >>= 1) s += __shfl_xor(s, off);
            if (lane == 0) dotP[b * 4 + wv] = s;
        }
    }
    __syncthreads();

    if (tid < NB) {
        float d = ((dotP[tid*4+0] + dotP[tid*4+1]) + (dotP[tid*4+2] + dotP[tid*4+3])) / nrm;
        out[OUT_DIST + (size_t)(bg0 + tid) * BS + bs] = 2.f - 2.f * d;
    }
}

extern "C" void kernel_launch(void* const* d_in, const int* in_sizes, int n_in,
                              void* d_out, int out_size, void* d_ws, size_t ws_size,
                              hipStream_t stream) {
    const float* sat = (const float*)d_in[0];
    const float* grd = (const float*)d_in[1];
    float* out = (float*)d_out;

    hipMemcpyAsync(out,             sat, (size_t)SAT_ELEMS * sizeof(float),
                   hipMemcpyDeviceToDevice, stream);
    hipMemcpyAsync(out + SAT_ELEMS, grd, (size_t)SAT_ELEMS * sizeof(float),
                   hipMemcpyDeviceToDevice, stream);

    dim3 grid(BG / NB, BS);   // (12, 96)
    pf_fused_kernel<<<grid, NTH, 0, stream>>>(sat, grd, out);
}

// Round 6
// 119.227 us; speedup vs baseline: 2.7936x; 2.7936x over previous
//
#include <hip/hip_runtime.h>
#include <math.h>
#include <stdint.h>

// Problem: ProcessFeatures_83296595738632
// corr[bs,bg,i] = sum_{h,j,k} sat[bs,h,(i+j)%64,k] * grd[bg,h,j,15-k]
// orien = argmax_i corr (first-max); dot with cyclic shift orien, /||sat||
// distance[bg,bs] = 2-2*dot[bs,bg]; out: sat | grd | distance | orien(float)
//
// R6: MFMA path. corr = per-bs GEMM M=64(i) x N=96(bg) x K=4096(j,hk), with
// A = row-rotated satM (LDS, XOR-chunk swizzle) and B = pre-gathered grdR.
// bf16x4 split (hi/lo both operands, 4 products) => fp32-class accuracy.
// Kernels: prologue (split planes into ws) -> corr (MFMA, partial per
// j-quarter) -> epilogue (sum, argmax, norm, dot, distance).

#define BS   96
#define H    4
#define W    64
#define C    16
#define BG   96
#define HWC  (H*W*C)                  // 4096

#define SAT_ELEMS (BS*H*W*C)          // 393216
#define OUT_DIST  (2*SAT_ELEMS)       // 786432
#define OUT_ORIEN (OUT_DIST + BS*BG)  // 795648

// ws layout (ushorts then floats)
#define WS_SATH   0
#define WS_SATLO  (SAT_ELEMS)
#define WS_GRDH   (2*SAT_ELEMS)
#define WS_GRDLO  (3*SAT_ELEMS)
#define WS_PART_BYTES_OFF (4*(size_t)SAT_ELEMS*2)          // 3,145,728 B
#define PART_SLICE (BS*64*96)                              // 589824 floats
#define WS_NEEDED (WS_PART_BYTES_OFF + 4*(size_t)PART_SLICE*4)  // 12,582,912 B

typedef __attribute__((ext_vector_type(8)))  short short8v;
typedef __attribute__((ext_vector_type(16))) float f32x16;

// ---------------- prologue: bf16 hi/lo split planes ----------------
__device__ __forceinline__ void bsplit(float x, unsigned short& hi, unsigned short& lo) {
    unsigned int u = __float_as_uint(x);
    unsigned int r = (u + 0x7FFFu + ((u >> 16) & 1u)) >> 16;   // RNE to bf16
    hi = (unsigned short)r;
    float hf = __uint_as_float(r << 16);
    float l = x - hf;
    unsigned int ul = __float_as_uint(l);
    unsigned int rl = (ul + 0x7FFFu + ((ul >> 16) & 1u)) >> 16;
    lo = (unsigned short)rl;
}

__global__ __launch_bounds__(256)
void pf_prologue(const float* __restrict__ sat, const float* __restrict__ grd,
                 unsigned short* __restrict__ wsu)
{
    int t = blockIdx.x * 256 + threadIdx.x;        // < 393216
    // satM[bs][w][hk] = sat[bs][hk>>4][w][hk&15]
    {
        int bs = t >> 12, rem = t & 4095;
        int w = rem >> 6, hk = rem & 63;
        int h = hk >> 4, k = hk & 15;
        float x = sat[((bs * 4 + h) * 64 + w) * 16 + k];
        unsigned short hi, lo; bsplit(x, hi, lo);
        wsu[WS_SATH + t] = hi; wsu[WS_SATLO + t] = lo;
    }
    // grdB[j][bg][hk] = grd[bg][hk>>4][j][15-(hk&15)]
    {
        int j = t / 6144, rem = t - j * 6144;
        int bg = rem >> 6, hk = rem & 63;
        int h = hk >> 4, k = 15 - (hk & 15);
        float g = grd[((bg * 4 + h) * 64 + j) * 16 + k];
        unsigned short hi, lo; bsplit(g, hi, lo);
        wsu[WS_GRDH + t] = hi; wsu[WS_GRDLO + t] = lo;
    }
}

// ---------------- corr: MFMA bf16x4 ----------------
#define MFMA(a, b, c) __builtin_amdgcn_mfma_f32_32x32x16_bf16((a), (b), (c), 0, 0, 0)

__global__ __launch_bounds__(256)
void pf_corr(const unsigned short* __restrict__ wsu, float* __restrict__ part)
{
    __shared__ unsigned short sHi[4096], sLo[4096];   // satM planes, swizzled
    __shared__ float corrP[64 * 96];                  // 24 KB

    const int bs = blockIdx.y;
    const int jq = blockIdx.x;            // j in [jq*16, jq*16+16)
    const int tid = threadIdx.x;
    const int wv = tid >> 6, lane = tid & 63;
    const int mh = wv & 1, kh = wv >> 1;  // M-half, j-subrange of 8
    const int l31 = lane & 31, l5 = lane >> 5;

    // stage satM planes with chunk swizzle: chunk cc of row r at slot cc^(r&7)
    for (int c = tid; c < 512; c += 256) {
        int r = c >> 3, cc = c & 7;
        int src = bs * 4096 + r * 64 + cc * 8;
        int dst = r * 64 + ((cc ^ (r & 7)) * 8);
        *(short8v*)&sHi[dst] = *(const short8v*)&wsu[WS_SATH + src];
        *(short8v*)&sLo[dst] = *(const short8v*)&wsu[WS_SATLO + src];
    }
    __syncthreads();

    f32x16 acc0, acc1, acc2;
    #pragma unroll
    for (int i = 0; i < 16; ++i) { acc0[i] = 0.f; acc1[i] = 0.f; acc2[i] = 0.f; }

    const int rbase = mh * 32 + l31 + jq * 16 + kh * 8;

    for (int jj = 0; jj < 8; ++jj) {
        const int j = jq * 16 + kh * 8 + jj;
        const int r = (rbase + jj) & 63;
        const int rsw = r & 7;
        const int arow = r * 64;
        const int brow = (j * 96 + l31) * 64 + l5 * 8;
        #pragma unroll
        for (int q = 0; q < 4; ++q) {
            const int cc = q * 2 + l5;
            const int aoff = arow + ((cc ^ rsw) * 8);
            short8v ah = *(const short8v*)&sHi[aoff];
            short8v al = *(const short8v*)&sLo[aoff];
            const int boff = brow + q * 16;
            short8v bh0 = *(const short8v*)&wsu[WS_GRDH  + boff];
            short8v bl0 = *(const short8v*)&wsu[WS_GRDLO + boff];
            acc0 = MFMA(ah, bh0, acc0); acc0 = MFMA(ah, bl0, acc0);
            acc0 = MFMA(al, bh0, acc0); acc0 = MFMA(al, bl0, acc0);
            short8v bh1 = *(const short8v*)&wsu[WS_GRDH  + boff + 2048];
            short8v bl1 = *(const short8v*)&wsu[WS_GRDLO + boff + 2048];
            acc1 = MFMA(ah, bh1, acc1); acc1 = MFMA(ah, bl1, acc1);
            acc1 = MFMA(al, bh1, acc1); acc1 = MFMA(al, bl1, acc1);
            short8v bh2 = *(const short8v*)&wsu[WS_GRDH  + boff + 4096];
            short8v bl2 = *(const short8v*)&wsu[WS_GRDLO + boff + 4096];
            acc2 = MFMA(ah, bh2, acc2); acc2 = MFMA(ah, bl2, acc2);
            acc2 = MFMA(al, bh2, acc2); acc2 = MFMA(al, bl2, acc2);
        }
    }

    // combine kh halves in LDS: C/D row = (reg&3)+8*(reg>>2)+4*l5 (+mh*32), col = l31+nt*32
    __syncthreads();
    if (kh == 0) {
        #pragma unroll
        for (int reg = 0; reg < 16; ++reg) {
            int row = mh * 32 + (reg & 3) + 8 * (reg >> 2) + 4 * l5;
            corrP[row * 96 +      l31] = acc0[reg];
            corrP[row * 96 + 32 + l31] = acc1[reg];
            corrP[row * 96 + 64 + l31] = acc2[reg];
        }
    }
    __syncthreads();
    if (kh == 1) {
        #pragma unroll
        for (int reg = 0; reg < 16; ++reg) {
            int row = mh * 32 + (reg & 3) + 8 * (reg >> 2) + 4 * l5;
            corrP[row * 96 +      l31] += acc0[reg];
            corrP[row * 96 + 32 + l31] += acc1[reg];
            corrP[row * 96 + 64 + l31] += acc2[reg];
        }
    }
    __syncthreads();

    float4* dst = (float4*)&part[((size_t)jq * BS + bs) * 6144];
    const float4* src = (const float4*)corrP;
    for (int x = tid; x < 1536; x += 256) dst[x] = src[x];
}

// ---------------- epilogue: sum partials, argmax, norm, dot ----------------
__global__ __launch_bounds__(512)
void pf_epilogue(const float* __restrict__ sat, const float* __restrict__ grd,
                 const float* __restrict__ part, float* __restrict__ out)
{
    __shared__ float corrE[64 * 97];      // padded columns
    __shared__ int   orienL[96];
    __shared__ float nrmS;

    const int bs = blockIdx.x;
    const int tid = threadIdx.x;
    const int wv = tid >> 6, lane = tid & 63;

    for (int idx = tid; idx < 6144; idx += 512) {
        float s = part[0 * PART_SLICE + bs * 6144 + idx]
                + part[1 * PART_SLICE + bs * 6144 + idx]
                + part[2 * PART_SLICE + bs * 6144 + idx]
                + part[3 * PART_SLICE + bs * 6144 + idx];
        int row = idx / 96;
        int col = idx - row * 96;
        corrE[row * 97 + col] = s;
    }

    if (tid < 64) {
        float s = 0.f;
        #pragma unroll
        for (int h = 0; h < 4; ++h) {
            const float4* p = (const float4*)&sat[(((size_t)bs * 4 + h) * 64 + tid) * 16];
            #pragma unroll
            for (int c4 = 0; c4 < 4; ++c4) {
                float4 v = p[c4];
                s = fmaf(v.x, v.x, fmaf(v.y, v.y, fmaf(v.z, v.z, fmaf(v.w, v.w, s))));
            }
        }
        #pragma unroll
        for (int off = 32; off; off >>= 1) s += __shfl_xor(s, off);
        if (tid == 0) nrmS = sqrtf(s + 1e-8f);
    }
    __syncthreads();

    // argmax (first-max tie-break): wave wv handles bg = wv*12 .. +11
    for (int bb = 0; bb < 12; ++bb) {
        int bg = wv * 12 + bb;
        float v = corrE[lane * 97 + bg];
        int idx = lane;
        #pragma unroll
        for (int off = 32; off; off >>= 1) {
            float ov = __shfl_xor(v, off);
            int   oi = __shfl_xor(idx, off);
            if (ov > v || (ov == v && oi < idx)) { v = ov; idx = oi; }
        }
        if (lane == 0) {
            orienL[bg] = idx;
            out[OUT_ORIEN + bs * BG + bg] = (float)idx;
        }
    }
    __syncthreads();

    const float nrm = nrmS;
    for (int bb = 0; bb < 12; ++bb) {
        int bg = wv * 12 + bb;
        int orn = orienL[bg];
        int r = (lane + orn) & 63;
        float s = 0.f;
        #pragma unroll
        for (int h = 0; h < 4; ++h) {
            const float4* sp = (const float4*)&sat[(((size_t)bs * 4 + h) * 64 + r) * 16];
            const float4* gp = (const float4*)&grd[(((size_t)bg * 4 + h) * 64 + lane) * 16];
            #pragma unroll
            for (int c4 = 0; c4 < 4; ++c4) {
                float4 sv = sp[c4];
                float4 gv = gp[c4];
                s = fmaf(sv.x, gv.x, fmaf(sv.y, gv.y, fmaf(sv.z, gv.z, fmaf(sv.w, gv.w, s))));
            }
        }
        #pragma unroll
        for (int off = 32; off; off >>= 1) s += __shfl_xor(s, off);
        if (lane == 0)
            out[OUT_DIST + (size_t)bg * BS + bs] = 2.f - 2.f * (s / nrm);
    }
}

// ---------------- fallback (R3, verified): used only if ws too small ----------------
__device__ __forceinline__ int satIdxFB(int hw, int c4) {
    return hw * 16 + 4 * ((c4 + (hw >> 1)) & 3);
}
__device__ __forceinline__ float rot_add(int baddr, float p) {
    return __int_as_float(__builtin_amdgcn_ds_bpermute(baddr, __float_as_int(p)));
}
__device__ __forceinline__ float dot_rev(const float4 s0, const float4 s1,
                                         const float4 s2, const float4 s3,
                                         const float* __restrict__ g) {
    float p0 = fmaf(s0.x, g[15], fmaf(s0.y, g[14], fmaf(s0.z, g[13], s0.w * g[12])));
    float p1 = fmaf(s1.x, g[11], fmaf(s1.y, g[10], fmaf(s1.z, g[ 9], s1.w * g[ 8])));
    float p2 = fmaf(s2.x, g[ 7], fmaf(s2.y, g[ 6], fmaf(s2.z, g[ 5], s2.w * g[ 4])));
    float p3 = fmaf(s3.x, g[ 3], fmaf(s3.y, g[ 2], fmaf(s3.z, g[ 1], s3.w * g[ 0])));
    return (p0 + p1) + (p2 + p3);
}
#define NB 8
__global__ __launch_bounds__(256)
void pf_fused_fb(const float* __restrict__ sat, const float* __restrict__ grd,
                 float* __restrict__ out)
{
    __shared__ float satL[H * W * C];
    __shared__ float partL[NB * 4 * W];
    __shared__ float sumL[4];
    __shared__ float dotP[NB * 4];
    __shared__ int   orienL[NB];
    const int bs = blockIdx.y, bg0 = blockIdx.x * NB;
    const int tid = threadIdx.x, wv = tid >> 6, lane = tid & 63;
    const float4* sp = (const float4*)(sat + (((size_t)bs * H + wv) * W + lane) * C);
    const float4 s0 = sp[0], s1 = sp[1], s2 = sp[2], s3 = sp[3];
    { const int hw = wv * W + lane;
      *(float4*)&satL[satIdxFB(hw,0)] = s0; *(float4*)&satL[satIdxFB(hw,1)] = s1;
      *(float4*)&satL[satIdxFB(hw,2)] = s2; *(float4*)&satL[satIdxFB(hw,3)] = s3; }
    { float a = fmaf(s0.x,s0.x,fmaf(s0.y,s0.y,fmaf(s0.z,s0.z,s0.w*s0.w)));
      float b = fmaf(s1.x,s1.x,fmaf(s1.y,s1.y,fmaf(s1.z,s1.z,s1.w*s1.w)));
      float c = fmaf(s2.x,s2.x,fmaf(s2.y,s2.y,fmaf(s2.z,s2.z,s2.w*s2.w)));
      float d = fmaf(s3.x,s3.x,fmaf(s3.y,s3.y,fmaf(s3.z,s3.z,s3.w*s3.w)));
      float s = (a+b)+(c+d);
      #pragma unroll
      for (int off = 32; off; off >>= 1) s += __shfl_xor(s, off);
      if (lane == 0) sumL[wv] = s; }
    uint64_t gaddr = (uint64_t)(grd + (size_t)(bg0 * H + wv) * W * C);
    const float* gpB = (const float*)gaddr;
    #pragma unroll
    for (int bp = 0; bp < NB/2; ++bp) {
        const float* gA = gpB + (2*bp) * HWC;
        const float* gB2 = gpB + (2*bp+1) * HWC;
        float accA = 0.f, accB = 0.f;
        int baddr = lane << 2;
        #pragma unroll 2
        for (int j = 0; j < W; ++j) {
            float pA = dot_rev(s0,s1,s2,s3, gA + j*C);
            float pB = dot_rev(s0,s1,s2,s3, gB2 + j*C);
            accA += rot_add(baddr, pA); accB += rot_add(baddr, pB);
            baddr = (baddr + 4) & 255;
        }
        partL[((2*bp)*4 + wv)*W + lane] = accA;
        partL[((2*bp+1)*4 + wv)*W + lane] = accB;
    }
    __syncthreads();
    for (int b = wv; b < NB; b += 4) {
        float v = (partL[(b*4+0)*W+lane] + partL[(b*4+1)*W+lane])
                + (partL[(b*4+2)*W+lane] + partL[(b*4+3)*W+lane]);
        int idx = lane;
        #pragma unroll
        for (int off = 32; off; off >>= 1) {
            float ov = __shfl_xor(v, off); int oi = __shfl_xor(idx, off);
            if (ov > v || (ov == v && oi < idx)) { v = ov; idx = oi; }
        }
        if (lane == 0) { orienL[b] = idx; out[OUT_ORIEN + bs*BG + (bg0+b)] = (float)idx; }
    }
    __syncthreads();
    const float nrm = sqrtf(sumL[0]+sumL[1]+sumL[2]+sumL[3] + 1e-8f);
    { float dp[NB];
      #pragma unroll
      for (int b = 0; b < NB; ++b) {
          const int row = (lane + orienL[b]) & 63;
          const float* gRow = grd + (((size_t)(bg0+b)*H + wv)*W + lane)*C;
          float s = 0.f;
          #pragma unroll
          for (int c4 = 0; c4 < 4; ++c4) {
              float4 sv = *(const float4*)&satL[satIdxFB(wv*W+row, c4)];
              float4 gv = *(const float4*)(gRow + 4*c4);
              s = fmaf(sv.x,gv.x, fmaf(sv.y,gv.y, fmaf(sv.z,gv.z, fmaf(sv.w,gv.w, s))));
          }
          dp[b] = s;
      }
      #pragma unroll
      for (int b = 0; b < NB; ++b) {
          float s = dp[b];
          #pragma unroll
          for (int off = 32; off; off >>= 1) s += __shfl_xor(s, off);
          if (lane == 0) dotP[b*4 + wv] = s;
      } }
    __syncthreads();
    if (tid < NB) {
        float d = ((dotP[tid*4+0]+dotP[tid*4+1])+(dotP[tid*4+2]+dotP[tid*4+3])) / nrm;
        out[OUT_DIST + (size_t)(bg0+tid)*BS + bs] = 2.f - 2.f*d;
    }
}

extern "C" void kernel_launch(void* const* d_in, const int* in_sizes, int n_in,
                              void* d_out, int out_size, void* d_ws, size_t ws_size,
                              hipStream_t stream) {
    const float* sat = (const float*)d_in[0];
    const float* grd = (const float*)d_in[1];
    float* out = (float*)d_out;

    hipMemcpyAsync(out,             sat, (size_t)SAT_ELEMS * sizeof(float),
                   hipMemcpyDeviceToDevice, stream);
    hipMemcpyAsync(out + SAT_ELEMS, grd, (size_t)SAT_ELEMS * sizeof(float),
                   hipMemcpyDeviceToDevice, stream);

    if (ws_size < WS_NEEDED) {
        dim3 grid(BG / NB, BS);
        pf_fused_fb<<<grid, 256, 0, stream>>>(sat, grd, out);
        return;
    }

    unsigned short* wsu = (unsigned short*)d_ws;
    float* part = (float*)((char*)d_ws + WS_PART_BYTES_OFF);

    pf_prologue<<<SAT_ELEMS / 256, 256, 0, stream>>>(sat, grd, wsu);
    pf_corr<<<dim3(4, BS), 256, 0, stream>>>(wsu, part);
    pf_epilogue<<<BS, 512, 0, stream>>>(sat, grd, part, out);
}

// Round 7
// 103.245 us; speedup vs baseline: 3.2260x; 1.1548x over previous
//
#include <hip/hip_runtime.h>
#include <math.h>
#include <stdint.h>

// Problem: ProcessFeatures_83296595738632
// corr[bs,bg,i] = sum_{h,j,k} sat[bs,h,(i+j)%64,k] * grd[bg,h,j,15-k]
// orien = argmax_i corr (first-max); dot with cyclic shift orien, /||sat||
// distance[bg,bs] = 2-2*dot[bs,bg]; out: sat | grd | distance | orien(float)
//
// R7: single fused MFMA kernel per (bgq,bs): corr (bf16x4 split GEMM,
// M=64 shifts x N=32 bg x K=4096) + LDS reduce + argmax + fp32 dot +
// distance. Prologue only pre-splits grdR planes. No partial buffer,
// no epilogue kernel.

#define BS   96
#define H    4
#define W    64
#define C    16
#define BG   96
#define HWC  (H*W*C)                  // 4096

#define SAT_ELEMS (BS*H*W*C)          // 393216
#define OUT_DIST  (2*SAT_ELEMS)       // 786432
#define OUT_ORIEN (OUT_DIST + BS*BG)  // 795648

// ws layout (ushorts): grdR hi plane | grdR lo plane
#define WS_GRDH   0
#define WS_GRDLO  (SAT_ELEMS)
#define WS_NEEDED ((size_t)2 * SAT_ELEMS * 2)   // 1.5 MB

typedef __attribute__((ext_vector_type(4)))  short short4v;
typedef __attribute__((ext_vector_type(8)))  short short8v;
typedef __attribute__((ext_vector_type(16))) float f32x16;

__device__ __forceinline__ void bsplit(float x, unsigned short& hi, unsigned short& lo) {
    unsigned int u = __float_as_uint(x);
    unsigned int r = (u + 0x7FFFu + ((u >> 16) & 1u)) >> 16;   // RNE to bf16
    hi = (unsigned short)r;
    float hf = __uint_as_float(r << 16);
    float l = x - hf;
    unsigned int ul = __float_as_uint(l);
    unsigned int rl = (ul + 0x7FFFu + ((ul >> 16) & 1u)) >> 16;
    lo = (unsigned short)rl;
}

// ---------------- prologue: grdR bf16 hi/lo planes ----------------
// grdR[j][bg][hk] = grd[bg][hk>>4][j][15-(hk&15)]
__global__ __launch_bounds__(256)
void pf_split_grd(const float* __restrict__ grd, unsigned short* __restrict__ wsu)
{
    int t = blockIdx.x * 256 + threadIdx.x;        // < 393216
    int j = t / 6144, rem = t - j * 6144;
    int bg = rem >> 6, hk = rem & 63;
    int h = hk >> 4, k = 15 - (hk & 15);
    float g = grd[((bg * 4 + h) * 64 + j) * 16 + k];
    unsigned short hi, lo; bsplit(g, hi, lo);
    wsu[WS_GRDH + t] = hi; wsu[WS_GRDLO + t] = lo;
}

// ---------------- fused: corr MFMA + argmax + dot + distance ----------------
#define MFMA(a, b, c) __builtin_amdgcn_mfma_f32_32x32x16_bf16((a), (b), (c), 0, 0, 0)

__global__ __launch_bounds__(512)
void pf_fused(const float* __restrict__ sat, const float* __restrict__ grd,
              const unsigned short* __restrict__ wsu, float* __restrict__ out)
{
    __shared__ unsigned short sHi[4096], sLo[4096];   // satM planes, swizzled (16 KB)
    __shared__ float corrPart[4][64][33];             // 33.8 KB, padded cols
    __shared__ float redW[8];
    __shared__ int   orienL[32];

    const int bs  = blockIdx.y;
    const int bg0 = blockIdx.x * 32;
    const int tid = threadIdx.x;
    const int wv  = tid >> 6, lane = tid & 63;
    const int l31 = lane & 31, l5 = lane >> 5;
    const int mh  = wv & 1, kq = wv >> 1;   // M-half, K-quarter (16 j each)

    // ---- stage satM (swizzled bf16 hi/lo) + norm partial, from global f32 ----
    // satM[w][hk] = sat[bs][hk>>4][w][hk&15]; chunk cc=hk>>3 at slot cc^(w&7)
    {
        const float4* satB = (const float4*)(sat + (size_t)bs * HWC);
        float np = 0.f;
        #pragma unroll
        for (int t = tid; t < 1024; t += 512) {
            float4 v = satB[t];
            int e = 4 * t;
            int h = e >> 10, w = (e >> 4) & 63, k = e & 15;   // k % 4 == 0
            int cc = (h * 16 + k) >> 3;
            int dst = w * 64 + ((cc ^ (w & 7)) * 8) + (k & 7);
            short4v hv, lv;
            unsigned short hi, lo;
            bsplit(v.x, hi, lo); hv[0] = hi; lv[0] = lo;
            bsplit(v.y, hi, lo); hv[1] = hi; lv[1] = lo;
            bsplit(v.z, hi, lo); hv[2] = hi; lv[2] = lo;
            bsplit(v.w, hi, lo); hv[3] = hi; lv[3] = lo;
            *(short4v*)&sHi[dst] = hv;
            *(short4v*)&sLo[dst] = lv;
            np = fmaf(v.x, v.x, fmaf(v.y, v.y, fmaf(v.z, v.z, fmaf(v.w, v.w, np))));
        }
        #pragma unroll
        for (int off = 32; off; off >>= 1) np += __shfl_xor(np, off);
        if (lane == 0) redW[wv] = np;
    }
    __syncthreads();

    // ---- corr GEMM: bf16x4, wave = (mh, kq), tile 32x32, K-slice 1024 ----
    f32x16 acc;
    #pragma unroll
    for (int i = 0; i < 16; ++i) acc[i] = 0.f;

    const int rbase = mh * 32 + l31 + kq * 16;
    const unsigned short* __restrict__ gH = wsu + WS_GRDH;
    const unsigned short* __restrict__ gL = wsu + WS_GRDLO;

    #pragma unroll 2
    for (int jj = 0; jj < 16; ++jj) {
        const int j = kq * 16 + jj;
        const int r = (rbase + jj) & 63;
        const int rsw = r & 7;
        const int arow = r * 64;
        const int brow = (j * 96 + bg0 + l31) * 64 + l5 * 8;
        #pragma unroll
        for (int q = 0; q < 4; ++q) {
            const int cc = q * 2 + l5;
            const int aoff = arow + ((cc ^ rsw) * 8);
            short8v ah = *(const short8v*)&sHi[aoff];
            short8v al = *(const short8v*)&sLo[aoff];
            const int boff = brow + q * 16;
            short8v bh = *(const short8v*)&gH[boff];
            short8v bl = *(const short8v*)&gL[boff];
            acc = MFMA(ah, bh, acc);
            acc = MFMA(ah, bl, acc);
            acc = MFMA(al, bh, acc);
            acc = MFMA(al, bl, acc);
        }
    }

    // ---- C/D -> corrPart (row = (reg&3)+8*(reg>>2)+4*l5 + mh*32, col = l31) ----
    #pragma unroll
    for (int reg = 0; reg < 16; ++reg) {
        int row = mh * 32 + (reg & 3) + 8 * (reg >> 2) + 4 * l5;
        corrPart[kq][row][l31] = acc[reg];
    }
    __syncthreads();

    // ---- argmax per bg (first-max tie-break): wave wv -> bgc = wv*4..+3 ----
    #pragma unroll
    for (int u = 0; u < 4; ++u) {
        const int bgc = wv * 4 + u;
        float v = (corrPart[0][lane][bgc] + corrPart[1][lane][bgc])
                + (corrPart[2][lane][bgc] + corrPart[3][lane][bgc]);
        int idx = lane;
        #pragma unroll
        for (int off = 32; off; off >>= 1) {
            float ov = __shfl_xor(v, off);
            int   oi = __shfl_xor(idx, off);
            if (ov > v || (ov == v && oi < idx)) { v = ov; idx = oi; }
        }
        if (lane == 0) {
            orienL[bgc] = idx;
            out[OUT_ORIEN + bs * BG + bg0 + bgc] = (float)idx;
        }
    }
    __syncthreads();

    const float nrm = sqrtf(((redW[0] + redW[1]) + (redW[2] + redW[3]))
                          + ((redW[4] + redW[5]) + (redW[6] + redW[7])) + 1e-8f);

    // ---- fp32 dot + distance: wave wv -> bgc = wv*4..+3, lane = j ----
    #pragma unroll
    for (int u = 0; u < 4; ++u) {
        const int bgc = wv * 4 + u;
        const int bg = bg0 + bgc;
        const int r = (lane + orienL[bgc]) & 63;
        float s = 0.f;
        #pragma unroll
        for (int h = 0; h < 4; ++h) {
            const float4* sp = (const float4*)&sat[(((size_t)bs * 4 + h) * 64 + r) * 16];
            const float4* gp = (const float4*)&grd[(((size_t)bg * 4 + h) * 64 + lane) * 16];
            #pragma unroll
            for (int c4 = 0; c4 < 4; ++c4) {
                float4 sv = sp[c4];
                float4 gv = gp[c4];
                s = fmaf(sv.x, gv.x, fmaf(sv.y, gv.y, fmaf(sv.z, gv.z, fmaf(sv.w, gv.w, s))));
            }
        }
        #pragma unroll
        for (int off = 32; off; off >>= 1) s += __shfl_xor(s, off);
        if (lane == 0)
            out[OUT_DIST + (size_t)bg * BS + bs] = 2.f - 2.f * (s / nrm);
    }
}

// ---------------- fallback (R3, verified): used only if ws too small ----------------
__device__ __forceinline__ int satIdxFB(int hw, int c4) {
    return hw * 16 + 4 * ((c4 + (hw >> 1)) & 3);
}
__device__ __forceinline__ float rot_add(int baddr, float p) {
    return __int_as_float(__builtin_amdgcn_ds_bpermute(baddr, __float_as_int(p)));
}
__device__ __forceinline__ float dot_rev(const float4 s0, const float4 s1,
                                         const float4 s2, const float4 s3,
                                         const float* __restrict__ g) {
    float p0 = fmaf(s0.x, g[15], fmaf(s0.y, g[14], fmaf(s0.z, g[13], s0.w * g[12])));
    float p1 = fmaf(s1.x, g[11], fmaf(s1.y, g[10], fmaf(s1.z, g[ 9], s1.w * g[ 8])));
    float p2 = fmaf(s2.x, g[ 7], fmaf(s2.y, g[ 6], fmaf(s2.z, g[ 5], s2.w * g[ 4])));
    float p3 = fmaf(s3.x, g[ 3], fmaf(s3.y, g[ 2], fmaf(s3.z, g[ 1], s3.w * g[ 0])));
    return (p0 + p1) + (p2 + p3);
}
#define NB 8
__global__ __launch_bounds__(256)
void pf_fused_fb(const float* __restrict__ sat, const float* __restrict__ grd,
                 float* __restrict__ out)
{
    __shared__ float satL[H * W * C];
    __shared__ float partL[NB * 4 * W];
    __shared__ float sumL[4];
    __shared__ float dotP[NB * 4];
    __shared__ int   orienL[NB];
    const int bs = blockIdx.y, bg0 = blockIdx.x * NB;
    const int tid = threadIdx.x, wv = tid >> 6, lane = tid & 63;
    const float4* sp = (const float4*)(sat + (((size_t)bs * H + wv) * W + lane) * C);
    const float4 s0 = sp[0], s1 = sp[1], s2 = sp[2], s3 = sp[3];
    { const int hw = wv * W + lane;
      *(float4*)&satL[satIdxFB(hw,0)] = s0; *(float4*)&satL[satIdxFB(hw,1)] = s1;
      *(float4*)&satL[satIdxFB(hw,2)] = s2; *(float4*)&satL[satIdxFB(hw,3)] = s3; }
    { float a = fmaf(s0.x,s0.x,fmaf(s0.y,s0.y,fmaf(s0.z,s0.z,s0.w*s0.w)));
      float b = fmaf(s1.x,s1.x,fmaf(s1.y,s1.y,fmaf(s1.z,s1.z,s1.w*s1.w)));
      float c = fmaf(s2.x,s2.x,fmaf(s2.y,s2.y,fmaf(s2.z,s2.z,s2.w*s2.w)));
      float d = fmaf(s3.x,s3.x,fmaf(s3.y,s3.y,fmaf(s3.z,s3.z,s3.w*s3.w)));
      float s = (a+b)+(c+d);
      #pragma unroll
      for (int off = 32; off; off >>= 1) s += __shfl_xor(s, off);
      if (lane == 0) sumL[wv] = s; }
    const float* gpB = grd + (size_t)(bg0 * H + wv) * W * C;
    #pragma unroll
    for (int bp = 0; bp < NB/2; ++bp) {
        const float* gA = gpB + (2*bp) * HWC;
        const float* gB2 = gpB + (2*bp+1) * HWC;
        float accA = 0.f, accB = 0.f;
        int baddr = lane << 2;
        #pragma unroll 2
        for (int j = 0; j < W; ++j) {
            float pA = dot_rev(s0,s1,s2,s3, gA + j*C);
            float pB = dot_rev(s0,s1,s2,s3, gB2 + j*C);
            accA += rot_add(baddr, pA); accB += rot_add(baddr, pB);
            baddr = (baddr + 4) & 255;
        }
        partL[((2*bp)*4 + wv)*W + lane] = accA;
        partL[((2*bp+1)*4 + wv)*W + lane] = accB;
    }
    __syncthreads();
    for (int b = wv; b < NB; b += 4) {
        float v = (partL[(b*4+0)*W+lane] + partL[(b*4+1)*W+lane])
                + (partL[(b*4+2)*W+lane] + partL[(b*4+3)*W+lane]);
        int idx = lane;
        #pragma unroll
        for (int off = 32; off; off >>= 1) {
            float ov = __shfl_xor(v, off); int oi = __shfl_xor(idx, off);
            if (ov > v || (ov == v && oi < idx)) { v = ov; idx = oi; }
        }
        if (lane == 0) { orienL[b] = idx; out[OUT_ORIEN + bs*BG + (bg0+b)] = (float)idx; }
    }
    __syncthreads();
    const float nrm = sqrtf(sumL[0]+sumL[1]+sumL[2]+sumL[3] + 1e-8f);
    { float dp[NB];
      #pragma unroll
      for (int b = 0; b < NB; ++b) {
          const int row = (lane + orienL[b]) & 63;
          const float* gRow = grd + (((size_t)(bg0+b)*H + wv)*W + lane)*C;
          float s = 0.f;
          #pragma unroll
          for (int c4 = 0; c4 < 4; ++c4) {
              float4 sv = *(const float4*)&satL[satIdxFB(wv*W+row, c4)];
              float4 gv = *(const float4*)(gRow + 4*c4);
              s = fmaf(sv.x,gv.x, fmaf(sv.y,gv.y, fmaf(sv.z,gv.z, fmaf(sv.w,gv.w, s))));
          }
          dp[b] = s;
      }
      #pragma unroll
      for (int b = 0; b < NB; ++b) {
          float s = dp[b];
          #pragma unroll
          for (int off = 32; off; off >>= 1) s += __shfl_xor(s, off);
          if (lane == 0) dotP[b*4 + wv] = s;
      } }
    __syncthreads();
    if (tid < NB) {
        float d = ((dotP[tid*4+0]+dotP[tid*4+1])+(dotP[tid*4+2]+dotP[tid*4+3])) / nrm;
        out[OUT_DIST + (size_t)(bg0+tid)*BS + bs] = 2.f - 2.f*d;
    }
}

extern "C" void kernel_launch(void* const* d_in, const int* in_sizes, int n_in,
                              void* d_out, int out_size, void* d_ws, size_t ws_size,
                              hipStream_t stream) {
    const float* sat = (const float*)d_in[0];
    const float* grd = (const float*)d_in[1];
    float* out = (float*)d_out;

    hipMemcpyAsync(out,             sat, (size_t)SAT_ELEMS * sizeof(float),
                   hipMemcpyDeviceToDevice, stream);
    hipMemcpyAsync(out + SAT_ELEMS, grd, (size_t)SAT_ELEMS * sizeof(float),
                   hipMemcpyDeviceToDevice, stream);

    if (ws_size < WS_NEEDED) {
        dim3 grid(BG / NB, BS);
        pf_fused_fb<<<grid, 256, 0, stream>>>(sat, grd, out);
        return;
    }

    unsigned short* wsu = (unsigned short*)d_ws;
    pf_split_grd<<<SAT_ELEMS / 256, 256, 0, stream>>>(grd, wsu);
    pf_fused<<<dim3(3, BS), 512, 0, stream>>>(sat, grd, wsu, out);
}

// Round 8
// 69.816 us; speedup vs baseline: 4.7707x; 1.4788x over previous
//
#include <hip/hip_runtime.h>
#include <math.h>
#include <stdint.h>

// Problem: ProcessFeatures_83296595738632
// corr[bs,bg,i] = sum_{h,j,k} sat[bs,h,(i+j)%64,k] * grd[bg,h,j,15-k]
// orien = argmax_i corr (first-max); dot with cyclic shift orien, /||sat||
// distance[bg,bs] = 2-2*dot[bs,bg]; out: sat | grd | distance | orien(float)
//
// R8: fused MFMA kernel (bf16x4 split GEMM) with:
//  - B pre-packed in FRAGMENT ORDER: Bpk[j][bgq][q][plane][lane][8]
//    -> every wave B-load is one contiguous, fully-coalesced 1 KB chunk
//  - explicit double-buffered B prefetch (8 fragments in flight)
//  - split accumulators (halve MFMA dependency chain)
//  - launch_bounds(512,2): allow up to 256 VGPR for pipelining

#define BS   96
#define H    4
#define W    64
#define C    16
#define BG   96
#define HWC  (H*W*C)                  // 4096

#define SAT_ELEMS (BS*H*W*C)          // 393216
#define OUT_DIST  (2*SAT_ELEMS)       // 786432
#define OUT_ORIEN (OUT_DIST + BS*BG)  // 795648

// ws: Bpk ushorts, fragment-ordered: idx = ((((j*3+bgq)*4+q)*2+pl)<<9) + lane*8 + e
#define WS_NEEDED ((size_t)2 * SAT_ELEMS * 2)   // 1.5 MB

typedef __attribute__((ext_vector_type(4)))  short short4v;
typedef __attribute__((ext_vector_type(8)))  short short8v;
typedef __attribute__((ext_vector_type(16))) float f32x16;

__device__ __forceinline__ void bsplit(float x, unsigned short& hi, unsigned short& lo) {
    unsigned int u = __float_as_uint(x);
    unsigned int r = (u + 0x7FFFu + ((u >> 16) & 1u)) >> 16;   // RNE to bf16
    hi = (unsigned short)r;
    float hf = __uint_as_float(r << 16);
    float l = x - hf;
    unsigned int ul = __float_as_uint(l);
    unsigned int rl = (ul + 0x7FFFu + ((ul >> 16) & 1u)) >> 16;
    lo = (unsigned short)rl;
}

// ---------------- prologue: pack B fragments ----------------
// Bpk fragment (j,bgq,q,pl,lane,e) = plane pl of grdR[j][bgq*32+(lane&31)][q*16+(lane>>5)*8+e]
// grdR[j][bg][hk] = grd[bg][hk>>4][j][15-(hk&15)];  hk in [16q,16q+16) -> h = q.
__global__ __launch_bounds__(512)
void pf_pack_b(const float* __restrict__ grd, unsigned short* __restrict__ Bpk)
{
    int t = blockIdx.x * 512 + threadIdx.x;    // < 49152 = 64*3*4*64
    int lane = t & 63;
    int q    = (t >> 6) & 3;
    int bgq  = (t >> 8) % 3;
    int j    = t / 768;
    int l31 = lane & 31, l5 = lane >> 5;
    int bg = bgq * 32 + l31;

    const float* row = grd + ((size_t)(bg * 4 + q) * 64 + j) * 16 + (8 - 8 * l5);
    float tmp[8];
    *(float4*)&tmp[0] = *(const float4*)(row);
    *(float4*)&tmp[4] = *(const float4*)(row + 4);

    short8v hv, lv;
    #pragma unroll
    for (int e = 0; e < 8; ++e) {
        unsigned short hi, lo;
        bsplit(tmp[7 - e], hi, lo);          // value[e] = row[7-e]  (k = 15-8*l5-e)
        hv[e] = (short)hi; lv[e] = (short)lo;
    }
    size_t base = ((size_t)((j * 3 + bgq) * 4 + q) * 2) << 9;
    *(short8v*)&Bpk[base + lane * 8]       = hv;   // plane 0 (hi)
    *(short8v*)&Bpk[base + 512 + lane * 8] = lv;   // plane 1 (lo)
}

// ---------------- fused: corr MFMA + argmax + dot + distance ----------------
#define MFMA(a, b, c) __builtin_amdgcn_mfma_f32_32x32x16_bf16((a), (b), (c), 0, 0, 0)

__global__ __launch_bounds__(512, 2)
void pf_fused(const float* __restrict__ sat, const float* __restrict__ grd,
              const unsigned short* __restrict__ Bpk, float* __restrict__ out)
{
    __shared__ unsigned short sHi[4096], sLo[4096];   // satM planes, swizzled (16 KB)
    __shared__ float corrPart[4][64][33];             // 33.8 KB
    __shared__ float redW[8];
    __shared__ int   orienL[32];

    const int bs  = blockIdx.y;
    const int bgq = blockIdx.x;
    const int bg0 = bgq * 32;
    const int tid = threadIdx.x;
    const int wv  = tid >> 6, lane = tid & 63;
    const int l31 = lane & 31, l5 = lane >> 5;
    const int mh  = wv & 1, kq = wv >> 1;   // M-half, K-quarter (16 j each)

    // ---- stage satM (swizzled bf16 hi/lo) + norm partial ----
    // satM[w][hk] = sat[bs][hk>>4][w][hk&15]; chunk cc=hk>>3 at slot cc^(w&7)
    {
        const float4* satB = (const float4*)(sat + (size_t)bs * HWC);
        float np = 0.f;
        #pragma unroll
        for (int t = tid; t < 1024; t += 512) {
            float4 v = satB[t];
            int e = 4 * t;
            int h = e >> 10, w = (e >> 4) & 63, k = e & 15;
            int cc = (h * 16 + k) >> 3;
            int dst = w * 64 + ((cc ^ (w & 7)) * 8) + (k & 7);
            short4v hvv, lvv;
            unsigned short hi, lo;
            bsplit(v.x, hi, lo); hvv[0] = hi; lvv[0] = lo;
            bsplit(v.y, hi, lo); hvv[1] = hi; lvv[1] = lo;
            bsplit(v.z, hi, lo); hvv[2] = hi; lvv[2] = lo;
            bsplit(v.w, hi, lo); hvv[3] = hi; lvv[3] = lo;
            *(short4v*)&sHi[dst] = hvv;
            *(short4v*)&sLo[dst] = lvv;
            np = fmaf(v.x, v.x, fmaf(v.y, v.y, fmaf(v.z, v.z, fmaf(v.w, v.w, np))));
        }
        #pragma unroll
        for (int off = 32; off; off >>= 1) np += __shfl_xor(np, off);
        if (lane == 0) redW[wv] = np;
    }
    __syncthreads();

    // ---- corr GEMM: bf16x4, wave = (mh, kq), tile 32x32, K-slice 1024 ----
    f32x16 accA, accB;
    #pragma unroll
    for (int i = 0; i < 16; ++i) { accA[i] = 0.f; accB[i] = 0.f; }

    const int rbase = mh * 32 + l31 + kq * 16;
    const int laneB = lane * 8;

    // B fragment address (ushort index); f = q*2 + plane
    #define BIDX(j, f) ((((size_t)((j) * 3 + bgq) * 8 + (f)) << 9) + laneB)

    short8v b0[8], b1[8];
    {
        const int j0 = kq * 16;
        #pragma unroll
        for (int f = 0; f < 8; ++f) b0[f] = *(const short8v*)&Bpk[BIDX(j0, f)];
    }

    #pragma unroll
    for (int jj = 0; jj < 16; ++jj) {
        const int j = kq * 16 + jj;
        // prefetch next jj's 8 B fragments into the other buffer
        if (jj < 15) {
            if ((jj & 1) == 0) {
                #pragma unroll
                for (int f = 0; f < 8; ++f) b1[f] = *(const short8v*)&Bpk[BIDX(j + 1, f)];
            } else {
                #pragma unroll
                for (int f = 0; f < 8; ++f) b0[f] = *(const short8v*)&Bpk[BIDX(j + 1, f)];
            }
        }
        const int r = (rbase + jj) & 63;
        const int rsw = r & 7;
        const int arow = r * 64;
        #pragma unroll
        for (int q = 0; q < 4; ++q) {
            const int cc = q * 2 + l5;
            const int aoff = arow + ((cc ^ rsw) * 8);
            short8v ah = *(const short8v*)&sHi[aoff];
            short8v al = *(const short8v*)&sLo[aoff];
            short8v bh = ((jj & 1) == 0) ? b0[q * 2] : b1[q * 2];
            short8v bl = ((jj & 1) == 0) ? b0[q * 2 + 1] : b1[q * 2 + 1];
            if (q < 2) {
                accA = MFMA(ah, bh, accA);
                accA = MFMA(ah, bl, accA);
                accA = MFMA(al, bh, accA);
                accA = MFMA(al, bl, accA);
            } else {
                accB = MFMA(ah, bh, accB);
                accB = MFMA(ah, bl, accB);
                accB = MFMA(al, bh, accB);
                accB = MFMA(al, bl, accB);
            }
        }
    }
    #undef BIDX

    // ---- C/D -> corrPart (row = (reg&3)+8*(reg>>2)+4*l5 + mh*32, col = l31) ----
    #pragma unroll
    for (int reg = 0; reg < 16; ++reg) {
        int row = mh * 32 + (reg & 3) + 8 * (reg >> 2) + 4 * l5;
        corrPart[kq][row][l31] = accA[reg] + accB[reg];
    }
    __syncthreads();

    // ---- argmax per bg (first-max tie-break): wave wv -> bgc = wv*4..+3 ----
    #pragma unroll
    for (int u = 0; u < 4; ++u) {
        const int bgc = wv * 4 + u;
        float v = (corrPart[0][lane][bgc] + corrPart[1][lane][bgc])
                + (corrPart[2][lane][bgc] + corrPart[3][lane][bgc]);
        int idx = lane;
        #pragma unroll
        for (int off = 32; off; off >>= 1) {
            float ov = __shfl_xor(v, off);
            int   oi = __shfl_xor(idx, off);
            if (ov > v || (ov == v && oi < idx)) { v = ov; idx = oi; }
        }
        if (lane == 0) {
            orienL[bgc] = idx;
            out[OUT_ORIEN + bs * BG + bg0 + bgc] = (float)idx;
        }
    }
    __syncthreads();

    const float nrm = sqrtf(((redW[0] + redW[1]) + (redW[2] + redW[3]))
                          + ((redW[4] + redW[5]) + (redW[6] + redW[7])) + 1e-8f);

    // ---- fp32 dot + distance: wave wv -> bgc = wv*4..+3, lane = j ----
    #pragma unroll
    for (int u = 0; u < 4; ++u) {
        const int bgc = wv * 4 + u;
        const int bg = bg0 + bgc;
        const int r = (lane + orienL[bgc]) & 63;
        float s = 0.f;
        #pragma unroll
        for (int h = 0; h < 4; ++h) {
            const float4* sp = (const float4*)&sat[(((size_t)bs * 4 + h) * 64 + r) * 16];
            const float4* gp = (const float4*)&grd[(((size_t)bg * 4 + h) * 64 + lane) * 16];
            #pragma unroll
            for (int c4 = 0; c4 < 4; ++c4) {
                float4 sv = sp[c4];
                float4 gv = gp[c4];
                s = fmaf(sv.x, gv.x, fmaf(sv.y, gv.y, fmaf(sv.z, gv.z, fmaf(sv.w, gv.w, s))));
            }
        }
        #pragma unroll
        for (int off = 32; off; off >>= 1) s += __shfl_xor(s, off);
        if (lane == 0)
            out[OUT_DIST + (size_t)bg * BS + bs] = 2.f - 2.f * (s / nrm);
    }
}

// ---------------- fallback (R3, verified): used only if ws too small ----------------
__device__ __forceinline__ int satIdxFB(int hw, int c4) {
    return hw * 16 + 4 * ((c4 + (hw >> 1)) & 3);
}
__device__ __forceinline__ float rot_add(int baddr, float p) {
    return __int_as_float(__builtin_amdgcn_ds_bpermute(baddr, __float_as_int(p)));
}
__device__ __forceinline__ float dot_rev(const float4 s0, const float4 s1,
                                         const float4 s2, const float4 s3,
                                         const float* __restrict__ g) {
    float p0 = fmaf(s0.x, g[15], fmaf(s0.y, g[14], fmaf(s0.z, g[13], s0.w * g[12])));
    float p1 = fmaf(s1.x, g[11], fmaf(s1.y, g[10], fmaf(s1.z, g[ 9], s1.w * g[ 8])));
    float p2 = fmaf(s2.x, g[ 7], fmaf(s2.y, g[ 6], fmaf(s2.z, g[ 5], s2.w * g[ 4])));
    float p3 = fmaf(s3.x, g[ 3], fmaf(s3.y, g[ 2], fmaf(s3.z, g[ 1], s3.w * g[ 0])));
    return (p0 + p1) + (p2 + p3);
}
#define NB 8
__global__ __launch_bounds__(256)
void pf_fused_fb(const float* __restrict__ sat, const float* __restrict__ grd,
                 float* __restrict__ out)
{
    __shared__ float satL[H * W * C];
    __shared__ float partL[NB * 4 * W];
    __shared__ float sumL[4];
    __shared__ float dotP[NB * 4];
    __shared__ int   orienL[NB];
    const int bs = blockIdx.y, bg0 = blockIdx.x * NB;
    const int tid = threadIdx.x, wv = tid >> 6, lane = tid & 63;
    const float4* sp = (const float4*)(sat + (((size_t)bs * H + wv) * W + lane) * C);
    const float4 s0 = sp[0], s1 = sp[1], s2 = sp[2], s3 = sp[3];
    { const int hw = wv * W + lane;
      *(float4*)&satL[satIdxFB(hw,0)] = s0; *(float4*)&satL[satIdxFB(hw,1)] = s1;
      *(float4*)&satL[satIdxFB(hw,2)] = s2; *(float4*)&satL[satIdxFB(hw,3)] = s3; }
    { float a = fmaf(s0.x,s0.x,fmaf(s0.y,s0.y,fmaf(s0.z,s0.z,s0.w*s0.w)));
      float b = fmaf(s1.x,s1.x,fmaf(s1.y,s1.y,fmaf(s1.z,s1.z,s1.w*s1.w)));
      float c = fmaf(s2.x,s2.x,fmaf(s2.y,s2.y,fmaf(s2.z,s2.z,s2.w*s2.w)));
      float d = fmaf(s3.x,s3.x,fmaf(s3.y,s3.y,fmaf(s3.z,s3.z,s3.w*s3.w)));
      float s = (a+b)+(c+d);
      #pragma unroll
      for (int off = 32; off; off >>= 1) s += __shfl_xor(s, off);
      if (lane == 0) sumL[wv] = s; }
    const float* gpB = grd + (size_t)(bg0 * H + wv) * W * C;
    #pragma unroll
    for (int bp = 0; bp < NB/2; ++bp) {
        const float* gA = gpB + (2*bp) * HWC;
        const float* gB2 = gpB + (2*bp+1) * HWC;
        float accA = 0.f, accB = 0.f;
        int baddr = lane << 2;
        #pragma unroll 2
        for (int j = 0; j < W; ++j) {
            float pA = dot_rev(s0,s1,s2,s3, gA + j*C);
            float pB = dot_rev(s0,s1,s2,s3, gB2 + j*C);
            accA += rot_add(baddr, pA); accB += rot_add(baddr, pB);
            baddr = (baddr + 4) & 255;
        }
        partL[((2*bp)*4 + wv)*W + lane] = accA;
        partL[((2*bp+1)*4 + wv)*W + lane] = accB;
    }
    __syncthreads();
    for (int b = wv; b < NB; b += 4) {
        float v = (partL[(b*4+0)*W+lane] + partL[(b*4+1)*W+lane])
                + (partL[(b*4+2)*W+lane] + partL[(b*4+3)*W+lane]);
        int idx = lane;
        #pragma unroll
        for (int off = 32; off; off >>= 1) {
            float ov = __shfl_xor(v, off); int oi = __shfl_xor(idx, off);
            if (ov > v || (ov == v && oi < idx)) { v = ov; idx = oi; }
        }
        if (lane == 0) { orienL[b] = idx; out[OUT_ORIEN + bs*BG + (bg0+b)] = (float)idx; }
    }
    __syncthreads();
    const float nrm = sqrtf(sumL[0]+sumL[1]+sumL[2]+sumL[3] + 1e-8f);
    { float dp[NB];
      #pragma unroll
      for (int b = 0; b < NB; ++b) {
          const int row = (lane + orienL[b]) & 63;
          const float* gRow = grd + (((size_t)(bg0+b)*H + wv)*W + lane)*C;
          float s = 0.f;
          #pragma unroll
          for (int c4 = 0; c4 < 4; ++c4) {
              float4 sv = *(const float4*)&satL[satIdxFB(wv*W+row, c4)];
              float4 gv = *(const float4*)(gRow + 4*c4);
              s = fmaf(sv.x,gv.x, fmaf(sv.y,gv.y, fmaf(sv.z,gv.z, fmaf(sv.w,gv.w, s))));
          }
          dp[b] = s;
      }
      #pragma unroll
      for (int b = 0; b < NB; ++b) {
          float s = dp[b];
          #pragma unroll
          for (int off = 32; off; off >>= 1) s += __shfl_xor(s, off);
          if (lane == 0) dotP[b*4 + wv] = s;
      } }
    __syncthreads();
    if (tid < NB) {
        float d = ((dotP[tid*4+0]+dotP[tid*4+1])+(dotP[tid*4+2]+dotP[tid*4+3])) / nrm;
        out[OUT_DIST + (size_t)(bg0+tid)*BS + bs] = 2.f - 2.f*d;
    }
}

extern "C" void kernel_launch(void* const* d_in, const int* in_sizes, int n_in,
                              void* d_out, int out_size, void* d_ws, size_t ws_size,
                              hipStream_t stream) {
    const float* sat = (const float*)d_in[0];
    const float* grd = (const float*)d_in[1];
    float* out = (float*)d_out;

    hipMemcpyAsync(out,             sat, (size_t)SAT_ELEMS * sizeof(float),
                   hipMemcpyDeviceToDevice, stream);
    hipMemcpyAsync(out + SAT_ELEMS, grd, (size_t)SAT_ELEMS * sizeof(float),
                   hipMemcpyDeviceToDevice, stream);

    if (ws_size < WS_NEEDED) {
        dim3 grid(BG / NB, BS);
        pf_fused_fb<<<grid, 256, 0, stream>>>(sat, grd, out);
        return;
    }

    unsigned short* Bpk = (unsigned short*)d_ws;
    pf_pack_b<<<96, 512, 0, stream>>>(grd, Bpk);
    pf_fused<<<dim3(3, BS), 512, 0, stream>>>(sat, grd, Bpk, out);
}